// Round 5
// baseline (11002.792 us; speedup 1.0000x reference)
//
#include <hip/hip_runtime.h>
#include <math.h>

typedef __bf16 bf16;
typedef __bf16 bf16x8 __attribute__((ext_vector_type(8)));
typedef float f32x4 __attribute__((ext_vector_type(4)));

#define B_DIM 8192
#define H_DIM 1024
#define T_PAST 60
#define T_FUT 30

static __device__ __forceinline__ void gld_lds16(const void* g, void* l) {
  __builtin_amdgcn_global_load_lds(
      (const __attribute__((address_space(1))) void*)g,
      (__attribute__((address_space(3))) void*)l, 16, 0, 0);
}

static __device__ __forceinline__ float sigm(float x) {
  return 1.f / (1.f + __expf(-x));
}
static __device__ __forceinline__ float tanh_fast(float x) {
  float xc = fminf(fmaxf(x, -10.f), 10.f);
  float e = __expf(2.f * xc);
  return (e - 1.f) / (e + 1.f);
}

// ---------------- runtime dtype detection ---------------------------------
__global__ void detect_dtype(const unsigned int* __restrict__ words,
                             int* __restrict__ is_bf16) {
  const int lane = threadIdx.x;
  int cnt = 0;
  for (int i = 0; i < 64; i++) {
    const unsigned int w = words[lane + i * 64];
    const int e = (w >> 7) & 0xFF;
    cnt += (e >= 100 && e <= 135) ? 1 : 0;
  }
  for (int off = 32; off > 0; off >>= 1) cnt += __shfl_down(cnt, off);
  if (lane == 0) *is_bf16 = (cnt >= 2048) ? 1 : 0;
}

// ---------------- batched input normalization -> canonical bf16 -----------
struct ConvDesc { const void* src; bf16* dst; int n; };
struct ConvPack { ConvDesc d[15]; };

__global__ __launch_bounds__(256) void convert_all(ConvPack p,
                                                   const int* __restrict__ flag,
                                                   float* __restrict__ h0a,
                                                   float* __restrict__ h0b) {
  const int ti = blockIdx.y;
  const ConvDesc d = p.d[ti];
  const int bf = *flag;
  const long stride = (long)gridDim.x * 256 * 8;
  for (long base = ((long)blockIdx.x * 256 + threadIdx.x) * 8; base < d.n;
       base += stride) {
    if (base + 8 <= d.n) {
      float f[8];
      if (bf) {
        const uint4 v = *(const uint4*)((const char*)d.src + base * 2);
        *(uint4*)((char*)d.dst + base * 2) = v;
        if (ti == 0 && h0a) {
          const bf16* bv = (const bf16*)&v;
#pragma unroll
          for (int e = 0; e < 8; e++) f[e] = (float)bv[e];
        }
      } else {
        const float* s = (const float*)d.src + base;
        const float4 v0 = *(const float4*)s;
        const float4 v1 = *(const float4*)(s + 4);
        f[0] = v0.x; f[1] = v0.y; f[2] = v0.z; f[3] = v0.w;
        f[4] = v1.x; f[5] = v1.y; f[6] = v1.z; f[7] = v1.w;
        bf16 o[8];
#pragma unroll
        for (int e = 0; e < 8; e++) o[e] = (bf16)f[e];
        *(uint4*)((char*)d.dst + base * 2) = *(const uint4*)o;
      }
      if (ti == 0 && h0a) {
#pragma unroll
        for (int e = 0; e < 8; e++) { h0a[base + e] = f[e]; h0b[base + e] = f[e]; }
      }
    } else {
      for (long e = base; e < d.n; e++) {
        const float f = bf ? (float)((const bf16*)d.src)[e]
                           : ((const float*)d.src)[e];
        d.dst[e] = (bf16)f;
        if (ti == 0 && h0a) { h0a[e] = f; h0b[e] = f; }
      }
    }
  }
}

// ---------------- generic C = A[MxK] * B[NxK]^T (+bias, relu), bf16 out ----
template <bool RELU, bool GI_BIAS>
__global__ __launch_bounds__(256, 2) void gemm_bt(
    const bf16* __restrict__ A, const bf16* __restrict__ Bm,
    const bf16* __restrict__ bias1, const bf16* __restrict__ bias2,
    bf16* __restrict__ C, int K, int N)
{
  __shared__ __attribute__((aligned(16))) bf16 As[128 * 32];
  __shared__ __attribute__((aligned(16))) bf16 Bs[128 * 32];
  const int tid = threadIdx.x;
  const int wave = tid >> 6, lane = tid & 63;
  const int quad = lane >> 4, l16 = lane & 15;
  const int m0 = blockIdx.x * 128, n0 = blockIdx.y * 128;
  const int wm = (wave & 1) * 64, wn = (wave >> 1) * 64;
  f32x4 acc[4][4] = {};
  for (int k0 = 0; k0 < K; k0 += 32) {
#pragma unroll
    for (int rr = 0; rr < 2; rr++) {
      const int c = rr * 256 + tid;
      const int cg = (c & 3) ^ ((c >> 3) & 3);  // source swizzle
      gld_lds16(A + (size_t)(m0 + (c >> 2)) * K + (k0 + cg * 8),
                As + (size_t)(rr * 256 + wave * 64) * 8);
      gld_lds16(Bm + (size_t)(n0 + (c >> 2)) * K + (k0 + cg * 8),
                Bs + (size_t)(rr * 256 + wave * 64) * 8);
    }
    __syncthreads();
    bf16x8 af[4], bv[4];
#pragma unroll
    for (int t = 0; t < 4; t++) {
      const int ra = wm + t * 16 + l16;
      const int rb = wn + t * 16 + l16;
      af[t] = *(const bf16x8*)(As + (ra * 32 + (quad ^ ((ra >> 1) & 3)) * 8));
      bv[t] = *(const bf16x8*)(Bs + (rb * 32 + (quad ^ ((rb >> 1) & 3)) * 8));
    }
#pragma unroll
    for (int tm = 0; tm < 4; tm++)
#pragma unroll
      for (int tn = 0; tn < 4; tn++)
        acc[tm][tn] = __builtin_amdgcn_mfma_f32_16x16x32_bf16(af[tm], bv[tn], acc[tm][tn], 0, 0, 0);
    __syncthreads();
  }
#pragma unroll
  for (int tn = 0; tn < 4; tn++) {
    const int col = n0 + wn + tn * 16 + l16;
    float bias = (float)bias1[col];
    if (GI_BIAS) {
      if (col < 2 * H_DIM) bias += (float)bias2[col];  // fold bh into r,z gates only
    }
#pragma unroll
    for (int tm = 0; tm < 4; tm++) {
#pragma unroll
      for (int r = 0; r < 4; r++) {
        const int row = m0 + wm + tm * 16 + quad * 4 + r;
        float v = acc[tm][tn][r] + bias;
        if (RELU) v = fmaxf(v, 0.f);
        C[(size_t)row * N + col] = (bf16)v;
      }
    }
  }
}

// ---------------- fused GRU step ------------------------------------------
struct GruArgs {
  const bf16* h_in16; const float* h_in32;
  bf16* h_out16; float* h_out32;
  const bf16* gi;    // [B][3H] bf16, bi(+bh for r,z) folded
  const bf16* wh;    // [3H][H]
  const bf16* bh;    // [3H] (need n-part)
  const bf16* fcw;   // [4][H]
  float* proj;       // [B][projT][4] fp32 accum
  int projT, t, relu;
};

// Double-buffered single-barrier K-loop: per iter, barrier -> issue async
// gld_lds for tile k+1 into the other buffer -> ds_read+MFMA tile k. The
// compiler's vmcnt(0)-before-barrier then lands AFTER a full compute phase
// has covered the load latency.
__global__ __launch_bounds__(256, 2) void gru_step(GruArgs g1, GruArgs g2)
{
  const GruArgs G = (blockIdx.z == 0) ? g1 : g2;
  __shared__ __attribute__((aligned(16))) bf16 As[2][128 * 32];
  __shared__ __attribute__((aligned(16))) bf16 Bs[2][192 * 32];
  const int tid = threadIdx.x;
  const int wave = tid >> 6, lane = tid & 63;
  const int quad = lane >> 4, l16 = lane & 15;
  const int m0 = blockIdx.x * 128;
  const int j0 = blockIdx.y * 64;

  auto stage = [&](int kt, int buf) {
    const int k0 = kt * 32;
#pragma unroll
    for (int rr = 0; rr < 2; rr++) {
      const int c = rr * 256 + tid;
      const int cg = (c & 3) ^ ((c >> 3) & 3);
      gld_lds16(G.h_in16 + (size_t)(m0 + (c >> 2)) * H_DIM + (k0 + cg * 8),
                As[buf] + (size_t)(rr * 256 + wave * 64) * 8);
    }
#pragma unroll
    for (int rr = 0; rr < 3; rr++) {
      const int c = rr * 256 + tid;
      const int p = c >> 2;                              // packed row 0..191
      const int cg = (c & 3) ^ ((c >> 3) & 3);
      const int grow = (p >> 6) * H_DIM + j0 + (p & 63); // gate*H + j
      gld_lds16(G.wh + (size_t)grow * H_DIM + (k0 + cg * 8),
                Bs[buf] + (size_t)(rr * 256 + wave * 64) * 8);
    }
  };

  f32x4 acc[2][12] = {};
  stage(0, 0);
  for (int kt = 0; kt < 32; kt++) {
    const int cur = kt & 1;
    __syncthreads();                 // tile kt staged; prev buf reads done
    if (kt + 1 < 32) stage(kt + 1, cur ^ 1);
    bf16x8 af[2];
#pragma unroll
    for (int tm = 0; tm < 2; tm++) {
      const int ra = wave * 32 + tm * 16 + l16;
      af[tm] = *(const bf16x8*)(As[cur] + (ra * 32 + (quad ^ ((ra >> 1) & 3)) * 8));
    }
#pragma unroll
    for (int tn = 0; tn < 12; tn++) {
      const int rb = tn * 16 + l16;
      bf16x8 bv = *(const bf16x8*)(Bs[cur] + (rb * 32 + (quad ^ ((rb >> 1) & 3)) * 8));
      acc[0][tn] = __builtin_amdgcn_mfma_f32_16x16x32_bf16(af[0], bv, acc[0][tn], 0, 0, 0);
      acc[1][tn] = __builtin_amdgcn_mfma_f32_16x16x32_bf16(af[1], bv, acc[1][tn], 0, 0, 0);
    }
  }
  // ---- epilogue: GRU cell + projection partials ----
  float pp[2][4][4];
#pragma unroll
  for (int tm = 0; tm < 2; tm++)
#pragma unroll
    for (int r = 0; r < 4; r++)
#pragma unroll
      for (int i = 0; i < 4; i++) pp[tm][r][i] = 0.f;

#pragma unroll
  for (int tj = 0; tj < 4; tj++) {
    const int jj = tj * 16 + l16;
    const int j = j0 + jj;
    const float bhn = (float)G.bh[2 * H_DIM + j];
    float fw[4];
#pragma unroll
    for (int i = 0; i < 4; i++) fw[i] = (float)G.fcw[i * H_DIM + j];
#pragma unroll
    for (int tm = 0; tm < 2; tm++) {
#pragma unroll
      for (int r = 0; r < 4; r++) {
        const int row = m0 + wave * 32 + tm * 16 + quad * 4 + r;
        const size_t gb = (size_t)row * (3 * H_DIM) + j;
        const float gr = (float)G.gi[gb];
        const float gz = (float)G.gi[gb + H_DIM];
        const float gn = (float)G.gi[gb + 2 * H_DIM];
        const float hr = acc[tm][tj][r];
        const float hz = acc[tm][tj + 4][r];
        const float hn = acc[tm][tj + 8][r];
        const float rg = sigm(gr + hr);
        const float zg = sigm(gz + hz);
        const float ng = tanh_fast(gn + rg * (hn + bhn));  // bh_n stays inside r*(...)
        const size_t hidx = (size_t)row * H_DIM + j;
        const float hold = G.h_in32 ? G.h_in32[hidx] : (float)G.h_in16[hidx];
        const float hnew = (1.f - zg) * ng + zg * hold;
        if (G.h_out32) G.h_out32[hidx] = hnew;
        G.h_out16[hidx] = (bf16)hnew;
        const float act = G.relu ? fmaxf(hnew, 0.f) : hnew;
#pragma unroll
        for (int i = 0; i < 4; i++) pp[tm][r][i] += fw[i] * act;
      }
    }
  }
#pragma unroll
  for (int tm = 0; tm < 2; tm++)
#pragma unroll
    for (int r = 0; r < 4; r++)
#pragma unroll
      for (int i = 0; i < 4; i++) {
        float v = pp[tm][r][i];
        v += __shfl_xor(v, 1);
        v += __shfl_xor(v, 2);
        v += __shfl_xor(v, 4);
        v += __shfl_xor(v, 8);
        if (l16 == 0) {
          const int row = m0 + wave * 32 + tm * 16 + quad * 4 + r;
          atomicAdd(&G.proj[((size_t)row * G.projT + G.t) * 4 + i], v);
        }
      }
}

// ---------------- finalize: add fc biases, emit in detected dtype ---------
__global__ __launch_bounds__(256) void finalize(const float* __restrict__ p1,
                                                const float* __restrict__ p2,
                                                const bf16* __restrict__ fib,
                                                const bf16* __restrict__ fob,
                                                const int* __restrict__ flag,
                                                void* __restrict__ out, int n) {
  const int idx = blockIdx.x * 256 + threadIdx.x;
  if (idx >= n) return;
  const int R1 = B_DIM * T_PAST * 4;
  float v;
  if (idx < R1) {
    v = p1[idx] + (float)fib[idx & 3];
  } else {
    const int k = idx - R1;
    v = p2[k] + (float)fob[k & 3];
  }
  if (*flag) ((bf16*)out)[idx] = (bf16)v;
  else       ((float*)out)[idx] = v;
}

extern "C" void kernel_launch(void* const* d_in, const int* in_sizes, int n_in,
                              void* d_out, int out_size, void* d_ws, size_t ws_size,
                              hipStream_t stream)
{
  (void)n_in;
  char* w = (char*)d_ws;
  auto alloc = [&](size_t bytes) -> void* {
    void* p = (void*)w;
    w += (bytes + 255) & ~(size_t)255;
    return p;
  };
  int* flag = (int*)alloc(256);

  // canonical bf16 copies of the 15 tensor inputs
  bf16* canon[15];
  for (int i = 0; i < 15; i++) canon[i] = (bf16*)alloc((size_t)in_sizes[i] * 2);
  const bf16* ctx  = canon[0];
  const bf16* wc   = canon[1];
  const bf16* bc   = canon[2];
  const bf16* g1wi = canon[3];
  const bf16* g1wh = canon[4];
  const bf16* g1bi = canon[5];
  const bf16* g1bh = canon[6];
  const bf16* g2wi = canon[7];
  const bf16* g2wh = canon[8];
  const bf16* g2bi = canon[9];
  const bf16* g2bh = canon[10];
  const bf16* fiw  = canon[11];
  const bf16* fib  = canon[12];
  const bf16* fow  = canon[13];
  const bf16* fob  = canon[14];

  bf16* ec   = (bf16*)alloc((size_t)B_DIM * 512 * 2);
  bf16* gi1  = (bf16*)alloc((size_t)B_DIM * 3 * H_DIM * 2);
  bf16* gi2  = (bf16*)alloc((size_t)B_DIM * 3 * H_DIM * 2);
  bf16* h116[2] = {(bf16*)alloc((size_t)B_DIM * H_DIM * 2), (bf16*)alloc((size_t)B_DIM * H_DIM * 2)};
  bf16* h216[2] = {(bf16*)alloc((size_t)B_DIM * H_DIM * 2), (bf16*)alloc((size_t)B_DIM * H_DIM * 2)};
  float* proj1 = (float*)alloc((size_t)B_DIM * T_PAST * 4 * 4);
  float* proj2 = (float*)alloc((size_t)B_DIM * T_FUT * 4 * 4);
  float* h132[2] = {nullptr, nullptr};
  float* h232[2] = {nullptr, nullptr};
  const size_t used = (size_t)(w - (char*)d_ws);
  const size_t fp32_need = (size_t)4 * B_DIM * H_DIM * 4 + 4096;
  const bool fp32h = (ws_size > used) && ((ws_size - used) >= fp32_need);
  if (fp32h) {
    h132[0] = (float*)alloc((size_t)B_DIM * H_DIM * 4);
    h132[1] = (float*)alloc((size_t)B_DIM * H_DIM * 4);
    h232[0] = (float*)alloc((size_t)B_DIM * H_DIM * 4);
    h232[1] = (float*)alloc((size_t)B_DIM * H_DIM * 4);
  }

  // 1) detect input dtype (bf16 vs f32) from context values
  detect_dtype<<<1, 64, 0, stream>>>((const unsigned int*)d_in[0], flag);

  // 2) zero projection accumulators (ws is poisoned before every call)
  hipMemsetAsync(proj1, 0,
                 ((size_t)B_DIM * T_PAST * 4 + (size_t)B_DIM * T_FUT * 4) * 4, stream);

  // 3) normalize all inputs to canonical bf16 (+ fp32 master h from ctx)
  ConvPack cp;
  for (int i = 0; i < 15; i++) { cp.d[i].src = d_in[i]; cp.d[i].dst = canon[i]; cp.d[i].n = in_sizes[i]; }
  convert_all<<<dim3(4096, 15), 256, 0, stream>>>(cp, flag,
      fp32h ? h132[0] : nullptr, fp32h ? h232[0] : nullptr);

  // encoded_context = relu(ctx @ wc^T + bc)
  gemm_bt<true, false><<<dim3(64, 4), 256, 0, stream>>>(ctx, wc, bc, nullptr, ec, H_DIM, 512);
  // gi = ec @ wi^T + bi (+ bh for r,z gates)
  gemm_bt<false, true><<<dim3(64, 24), 256, 0, stream>>>(ec, g1wi, g1bi, g1bh, gi1, 512, 3 * H_DIM);
  gemm_bt<false, true><<<dim3(64, 24), 256, 0, stream>>>(ec, g2wi, g2bi, g2bh, gi2, 512, 3 * H_DIM);

  for (int t = 0; t < T_PAST; t++) {
    const int si = t & 1, so = (t + 1) & 1;
    GruArgs a1;
    a1.h_in16 = (t == 0) ? ctx : h116[si];
    a1.h_in32 = fp32h ? h132[si] : nullptr;
    a1.h_out16 = h116[so];
    a1.h_out32 = fp32h ? h132[so] : nullptr;
    a1.gi = gi1; a1.wh = g1wh; a1.bh = g1bh; a1.fcw = fiw;
    a1.proj = proj1; a1.projT = T_PAST; a1.t = t; a1.relu = 0;
    if (t < T_FUT) {
      GruArgs a2;
      a2.h_in16 = (t == 0) ? ctx : h216[si];
      a2.h_in32 = fp32h ? h232[si] : nullptr;
      a2.h_out16 = h216[so];
      a2.h_out32 = fp32h ? h232[so] : nullptr;
      a2.gi = gi2; a2.wh = g2wh; a2.bh = g2bh; a2.fcw = fow;
      a2.proj = proj2; a2.projT = T_FUT; a2.t = t; a2.relu = 1;
      gru_step<<<dim3(64, 16, 2), 256, 0, stream>>>(a1, a2);
    } else {
      gru_step<<<dim3(64, 16, 1), 256, 0, stream>>>(a1, a1);
    }
  }

  finalize<<<dim3((out_size + 255) / 256), 256, 0, stream>>>(
      proj1, proj2, fib, fob, flag, d_out, out_size);
}

// Round 6
// 9435.411 us; speedup vs baseline: 1.1661x; 1.1661x over previous
//
#include <hip/hip_runtime.h>
#include <math.h>

typedef __bf16 bf16;
typedef __bf16 bf16x8 __attribute__((ext_vector_type(8)));
typedef float f32x4 __attribute__((ext_vector_type(4)));

#define B_DIM 8192
#define H_DIM 1024
#define T_PAST 60
#define T_FUT 30

static __device__ __forceinline__ void gld_lds16(const void* g, void* l) {
  __builtin_amdgcn_global_load_lds(
      (const __attribute__((address_space(1))) void*)g,
      (__attribute__((address_space(3))) void*)l, 16, 0, 0);
}

static __device__ __forceinline__ float sigm(float x) {
  return 1.f / (1.f + __expf(-x));
}
static __device__ __forceinline__ float tanh_fast(float x) {
  float xc = fminf(fmaxf(x, -10.f), 10.f);
  float e = __expf(2.f * xc);
  return (e - 1.f) / (e + 1.f);
}

// ---------------- runtime dtype detection ---------------------------------
__global__ void detect_dtype(const unsigned int* __restrict__ words,
                             int* __restrict__ is_bf16) {
  const int lane = threadIdx.x;
  int cnt = 0;
  for (int i = 0; i < 64; i++) {
    const unsigned int w = words[lane + i * 64];
    const int e = (w >> 7) & 0xFF;
    cnt += (e >= 100 && e <= 135) ? 1 : 0;
  }
  for (int off = 32; off > 0; off >>= 1) cnt += __shfl_down(cnt, off);
  if (lane == 0) *is_bf16 = (cnt >= 2048) ? 1 : 0;
}

// ---------------- batched input normalization -> canonical bf16 -----------
struct ConvDesc { const void* src; bf16* dst; int n; };
struct ConvPack { ConvDesc d[15]; };

__global__ __launch_bounds__(256) void convert_all(ConvPack p,
                                                   const int* __restrict__ flag,
                                                   float* __restrict__ h0a,
                                                   float* __restrict__ h0b) {
  const int ti = blockIdx.y;
  const ConvDesc d = p.d[ti];
  const int bf = *flag;
  const long stride = (long)gridDim.x * 256 * 8;
  for (long base = ((long)blockIdx.x * 256 + threadIdx.x) * 8; base < d.n;
       base += stride) {
    if (base + 8 <= d.n) {
      float f[8];
      if (bf) {
        const uint4 v = *(const uint4*)((const char*)d.src + base * 2);
        *(uint4*)((char*)d.dst + base * 2) = v;
        if (ti == 0 && h0a) {
          const bf16* bv = (const bf16*)&v;
#pragma unroll
          for (int e = 0; e < 8; e++) f[e] = (float)bv[e];
        }
      } else {
        const float* s = (const float*)d.src + base;
        const float4 v0 = *(const float4*)s;
        const float4 v1 = *(const float4*)(s + 4);
        f[0] = v0.x; f[1] = v0.y; f[2] = v0.z; f[3] = v0.w;
        f[4] = v1.x; f[5] = v1.y; f[6] = v1.z; f[7] = v1.w;
        bf16 o[8];
#pragma unroll
        for (int e = 0; e < 8; e++) o[e] = (bf16)f[e];
        *(uint4*)((char*)d.dst + base * 2) = *(const uint4*)o;
      }
      if (ti == 0 && h0a) {
#pragma unroll
        for (int e = 0; e < 8; e++) { h0a[base + e] = f[e]; h0b[base + e] = f[e]; }
      }
    } else {
      for (long e = base; e < d.n; e++) {
        const float f = bf ? (float)((const bf16*)d.src)[e]
                           : ((const float*)d.src)[e];
        d.dst[e] = (bf16)f;
        if (ti == 0 && h0a) { h0a[e] = f; h0b[e] = f; }
      }
    }
  }
}

// ---------------- generic C = A[MxK] * B[NxK]^T (+bias, relu), bf16 out ----
template <bool RELU, bool GI_BIAS>
__global__ __launch_bounds__(256, 2) void gemm_bt(
    const bf16* __restrict__ A, const bf16* __restrict__ Bm,
    const bf16* __restrict__ bias1, const bf16* __restrict__ bias2,
    bf16* __restrict__ C, int K, int N)
{
  __shared__ __attribute__((aligned(16))) bf16 As[128 * 32];
  __shared__ __attribute__((aligned(16))) bf16 Bs[128 * 32];
  const int tid = threadIdx.x;
  const int wave = tid >> 6, lane = tid & 63;
  const int quad = lane >> 4, l16 = lane & 15;
  const int m0 = blockIdx.x * 128, n0 = blockIdx.y * 128;
  const int wm = (wave & 1) * 64, wn = (wave >> 1) * 64;
  f32x4 acc[4][4] = {};
  for (int k0 = 0; k0 < K; k0 += 32) {
#pragma unroll
    for (int rr = 0; rr < 2; rr++) {
      const int c = rr * 256 + tid;
      const int cg = (c & 3) ^ ((c >> 3) & 3);  // source swizzle
      gld_lds16(A + (size_t)(m0 + (c >> 2)) * K + (k0 + cg * 8),
                As + (size_t)(rr * 256 + wave * 64) * 8);
      gld_lds16(Bm + (size_t)(n0 + (c >> 2)) * K + (k0 + cg * 8),
                Bs + (size_t)(rr * 256 + wave * 64) * 8);
    }
    __syncthreads();
    bf16x8 af[4], bv[4];
#pragma unroll
    for (int t = 0; t < 4; t++) {
      const int ra = wm + t * 16 + l16;
      const int rb = wn + t * 16 + l16;
      af[t] = *(const bf16x8*)(As + (ra * 32 + (quad ^ ((ra >> 1) & 3)) * 8));
      bv[t] = *(const bf16x8*)(Bs + (rb * 32 + (quad ^ ((rb >> 1) & 3)) * 8));
    }
#pragma unroll
    for (int tm = 0; tm < 4; tm++)
#pragma unroll
      for (int tn = 0; tn < 4; tn++)
        acc[tm][tn] = __builtin_amdgcn_mfma_f32_16x16x32_bf16(af[tm], bv[tn], acc[tm][tn], 0, 0, 0);
    __syncthreads();
  }
#pragma unroll
  for (int tn = 0; tn < 4; tn++) {
    const int col = n0 + wn + tn * 16 + l16;
    float bias = (float)bias1[col];
    if (GI_BIAS) {
      if (col < 2 * H_DIM) bias += (float)bias2[col];  // fold bh into r,z gates only
    }
#pragma unroll
    for (int tm = 0; tm < 4; tm++) {
#pragma unroll
      for (int r = 0; r < 4; r++) {
        const int row = m0 + wm + tm * 16 + quad * 4 + r;
        float v = acc[tm][tn][r] + bias;
        if (RELU) v = fmaxf(v, 0.f);
        C[(size_t)row * N + col] = (bf16)v;
      }
    }
  }
}

// ---------------- fused GRU step ------------------------------------------
// Block: 64 batch rows x 64 hidden units, all 3 gate strips (packed N=192).
// 4 waves, each 16 rows x 192 cols -> acc[12] = 48 AGPR (vs 96 before),
// targeting 3 waves/SIMD occupancy. Single-buffered LDS (dbuf was neutral).
struct GruArgs {
  const bf16* h_in16; const float* h_in32;
  bf16* h_out16; float* h_out32;
  const bf16* gi;    // [B][3H] bf16, bi(+bh for r,z) folded
  const bf16* wh;    // [3H][H]
  const bf16* bh;    // [3H] (need n-part)
  const bf16* fcw;   // [4][H]
  float* proj;       // [B][projT][4] fp32 accum
  int projT, t, relu;
};

__global__ __launch_bounds__(256, 3) void gru_step(GruArgs g1, GruArgs g2)
{
  const GruArgs G = (blockIdx.z == 0) ? g1 : g2;
  __shared__ __attribute__((aligned(16))) bf16 As[64 * 32];
  __shared__ __attribute__((aligned(16))) bf16 Bs[192 * 32];
  const int tid = threadIdx.x;
  const int wave = tid >> 6, lane = tid & 63;
  const int quad = lane >> 4, l16 = lane & 15;
  const int m0 = blockIdx.x * 64;
  const int j0 = blockIdx.y * 64;
  f32x4 acc[12] = {};
  for (int k0 = 0; k0 < H_DIM; k0 += 32) {
    {
      const int c = tid;                                 // 64 rows x 4 chunks
      const int cg = (c & 3) ^ ((c >> 3) & 3);
      gld_lds16(G.h_in16 + (size_t)(m0 + (c >> 2)) * H_DIM + (k0 + cg * 8),
                As + (size_t)(wave * 64) * 8);
    }
#pragma unroll
    for (int rr = 0; rr < 3; rr++) {
      const int c = rr * 256 + tid;
      const int p = c >> 2;                              // packed row 0..191
      const int cg = (c & 3) ^ ((c >> 3) & 3);
      const int grow = (p >> 6) * H_DIM + j0 + (p & 63); // gate*H + j
      gld_lds16(G.wh + (size_t)grow * H_DIM + (k0 + cg * 8),
                Bs + (size_t)(rr * 256 + wave * 64) * 8);
    }
    __syncthreads();
    const int ra = wave * 16 + l16;
    bf16x8 af = *(const bf16x8*)(As + (ra * 32 + (quad ^ ((ra >> 1) & 3)) * 8));
#pragma unroll
    for (int tn = 0; tn < 12; tn++) {
      const int rb = tn * 16 + l16;
      bf16x8 bv = *(const bf16x8*)(Bs + (rb * 32 + (quad ^ ((rb >> 1) & 3)) * 8));
      acc[tn] = __builtin_amdgcn_mfma_f32_16x16x32_bf16(af, bv, acc[tn], 0, 0, 0);
    }
    __syncthreads();
  }
  // ---- epilogue: GRU cell + projection partials ----
  float pp[4][4];
#pragma unroll
  for (int r = 0; r < 4; r++)
#pragma unroll
    for (int i = 0; i < 4; i++) pp[r][i] = 0.f;

#pragma unroll
  for (int tj = 0; tj < 4; tj++) {
    const int j = j0 + tj * 16 + l16;
    const float bhn = (float)G.bh[2 * H_DIM + j];
    float fw[4];
#pragma unroll
    for (int i = 0; i < 4; i++) fw[i] = (float)G.fcw[i * H_DIM + j];
#pragma unroll
    for (int r = 0; r < 4; r++) {
      const int row = m0 + wave * 16 + quad * 4 + r;
      const size_t gb = (size_t)row * (3 * H_DIM) + j;
      const float gr = (float)G.gi[gb];
      const float gz = (float)G.gi[gb + H_DIM];
      const float gn = (float)G.gi[gb + 2 * H_DIM];
      const float hr = acc[tj][r];
      const float hz = acc[tj + 4][r];
      const float hn = acc[tj + 8][r];
      const float rg = sigm(gr + hr);
      const float zg = sigm(gz + hz);
      const float ng = tanh_fast(gn + rg * (hn + bhn));  // bh_n stays inside r*(...)
      const size_t hidx = (size_t)row * H_DIM + j;
      const float hold = G.h_in32 ? G.h_in32[hidx] : (float)G.h_in16[hidx];
      const float hnew = (1.f - zg) * ng + zg * hold;
      if (G.h_out32) G.h_out32[hidx] = hnew;
      G.h_out16[hidx] = (bf16)hnew;
      const float act = G.relu ? fmaxf(hnew, 0.f) : hnew;
#pragma unroll
      for (int i = 0; i < 4; i++) pp[r][i] += fw[i] * act;
    }
  }
#pragma unroll
  for (int r = 0; r < 4; r++)
#pragma unroll
    for (int i = 0; i < 4; i++) {
      float v = pp[r][i];
      v += __shfl_xor(v, 1);
      v += __shfl_xor(v, 2);
      v += __shfl_xor(v, 4);
      v += __shfl_xor(v, 8);
      if (l16 == 0) {
        const int row = m0 + wave * 16 + quad * 4 + r;
        atomicAdd(&G.proj[((size_t)row * G.projT + G.t) * 4 + i], v);
      }
    }
}

// ---------------- finalize: add fc biases, emit in detected dtype ---------
__global__ __launch_bounds__(256) void finalize(const float* __restrict__ p1,
                                                const float* __restrict__ p2,
                                                const bf16* __restrict__ fib,
                                                const bf16* __restrict__ fob,
                                                const int* __restrict__ flag,
                                                void* __restrict__ out, int n) {
  const int idx = blockIdx.x * 256 + threadIdx.x;
  if (idx >= n) return;
  const int R1 = B_DIM * T_PAST * 4;
  float v;
  if (idx < R1) {
    v = p1[idx] + (float)fib[idx & 3];
  } else {
    const int k = idx - R1;
    v = p2[k] + (float)fob[k & 3];
  }
  if (*flag) ((bf16*)out)[idx] = (bf16)v;
  else       ((float*)out)[idx] = v;
}

extern "C" void kernel_launch(void* const* d_in, const int* in_sizes, int n_in,
                              void* d_out, int out_size, void* d_ws, size_t ws_size,
                              hipStream_t stream)
{
  (void)n_in;
  char* w = (char*)d_ws;
  auto alloc = [&](size_t bytes) -> void* {
    void* p = (void*)w;
    w += (bytes + 255) & ~(size_t)255;
    return p;
  };
  int* flag = (int*)alloc(256);

  // canonical bf16 copies of the 15 tensor inputs
  bf16* canon[15];
  for (int i = 0; i < 15; i++) canon[i] = (bf16*)alloc((size_t)in_sizes[i] * 2);
  const bf16* ctx  = canon[0];
  const bf16* wc   = canon[1];
  const bf16* bc   = canon[2];
  const bf16* g1wi = canon[3];
  const bf16* g1wh = canon[4];
  const bf16* g1bi = canon[5];
  const bf16* g1bh = canon[6];
  const bf16* g2wi = canon[7];
  const bf16* g2wh = canon[8];
  const bf16* g2bi = canon[9];
  const bf16* g2bh = canon[10];
  const bf16* fiw  = canon[11];
  const bf16* fib  = canon[12];
  const bf16* fow  = canon[13];
  const bf16* fob  = canon[14];

  bf16* ec   = (bf16*)alloc((size_t)B_DIM * 512 * 2);
  bf16* gi1  = (bf16*)alloc((size_t)B_DIM * 3 * H_DIM * 2);
  bf16* gi2  = (bf16*)alloc((size_t)B_DIM * 3 * H_DIM * 2);
  bf16* h116[2] = {(bf16*)alloc((size_t)B_DIM * H_DIM * 2), (bf16*)alloc((size_t)B_DIM * H_DIM * 2)};
  bf16* h216[2] = {(bf16*)alloc((size_t)B_DIM * H_DIM * 2), (bf16*)alloc((size_t)B_DIM * H_DIM * 2)};
  float* proj1 = (float*)alloc((size_t)B_DIM * T_PAST * 4 * 4);
  float* proj2 = (float*)alloc((size_t)B_DIM * T_FUT * 4 * 4);
  float* h132[2] = {nullptr, nullptr};
  float* h232[2] = {nullptr, nullptr};
  const size_t used = (size_t)(w - (char*)d_ws);
  const size_t fp32_need = (size_t)4 * B_DIM * H_DIM * 4 + 4096;
  const bool fp32h = (ws_size > used) && ((ws_size - used) >= fp32_need);
  if (fp32h) {
    h132[0] = (float*)alloc((size_t)B_DIM * H_DIM * 4);
    h132[1] = (float*)alloc((size_t)B_DIM * H_DIM * 4);
    h232[0] = (float*)alloc((size_t)B_DIM * H_DIM * 4);
    h232[1] = (float*)alloc((size_t)B_DIM * H_DIM * 4);
  }

  // 1) detect input dtype (bf16 vs f32) from context values
  detect_dtype<<<1, 64, 0, stream>>>((const unsigned int*)d_in[0], flag);

  // 2) zero projection accumulators (ws is poisoned before every call)
  hipMemsetAsync(proj1, 0,
                 ((size_t)B_DIM * T_PAST * 4 + (size_t)B_DIM * T_FUT * 4) * 4, stream);

  // 3) normalize all inputs to canonical bf16 (+ fp32 master h from ctx)
  ConvPack cp;
  for (int i = 0; i < 15; i++) { cp.d[i].src = d_in[i]; cp.d[i].dst = canon[i]; cp.d[i].n = in_sizes[i]; }
  convert_all<<<dim3(4096, 15), 256, 0, stream>>>(cp, flag,
      fp32h ? h132[0] : nullptr, fp32h ? h232[0] : nullptr);

  // encoded_context = relu(ctx @ wc^T + bc)
  gemm_bt<true, false><<<dim3(64, 4), 256, 0, stream>>>(ctx, wc, bc, nullptr, ec, H_DIM, 512);
  // gi = ec @ wi^T + bi (+ bh for r,z gates)
  gemm_bt<false, true><<<dim3(64, 24), 256, 0, stream>>>(ec, g1wi, g1bi, g1bh, gi1, 512, 3 * H_DIM);
  gemm_bt<false, true><<<dim3(64, 24), 256, 0, stream>>>(ec, g2wi, g2bi, g2bh, gi2, 512, 3 * H_DIM);

  for (int t = 0; t < T_PAST; t++) {
    const int si = t & 1, so = (t + 1) & 1;
    GruArgs a1;
    a1.h_in16 = (t == 0) ? ctx : h116[si];
    a1.h_in32 = fp32h ? h132[si] : nullptr;
    a1.h_out16 = h116[so];
    a1.h_out32 = fp32h ? h132[so] : nullptr;
    a1.gi = gi1; a1.wh = g1wh; a1.bh = g1bh; a1.fcw = fiw;
    a1.proj = proj1; a1.projT = T_PAST; a1.t = t; a1.relu = 0;
    if (t < T_FUT) {
      GruArgs a2;
      a2.h_in16 = (t == 0) ? ctx : h216[si];
      a2.h_in32 = fp32h ? h232[si] : nullptr;
      a2.h_out16 = h216[so];
      a2.h_out32 = fp32h ? h232[so] : nullptr;
      a2.gi = gi2; a2.wh = g2wh; a2.bh = g2bh; a2.fcw = fow;
      a2.proj = proj2; a2.projT = T_FUT; a2.t = t; a2.relu = 1;
      gru_step<<<dim3(128, 16, 2), 256, 0, stream>>>(a1, a2);
    } else {
      gru_step<<<dim3(128, 16, 1), 256, 0, stream>>>(a1, a1);
    }
  }

  finalize<<<dim3((out_size + 255) / 256), 256, 0, stream>>>(
      proj1, proj2, fib, fob, flag, d_out, out_size);
}

// Round 7
// 9114.388 us; speedup vs baseline: 1.2072x; 1.0352x over previous
//
#include <hip/hip_runtime.h>
#include <math.h>

typedef __bf16 bf16;
typedef __bf16 bf16x8 __attribute__((ext_vector_type(8)));
typedef float f32x4 __attribute__((ext_vector_type(4)));

#define B_DIM 8192
#define H_DIM 1024
#define T_PAST 60
#define T_FUT 30

static __device__ __forceinline__ void gld_lds16(const void* g, void* l) {
  __builtin_amdgcn_global_load_lds(
      (const __attribute__((address_space(1))) void*)g,
      (__attribute__((address_space(3))) void*)l, 16, 0, 0);
}

static __device__ __forceinline__ float sigm(float x) {
  return 1.f / (1.f + __expf(-x));
}
static __device__ __forceinline__ float tanh_fast(float x) {
  float xc = fminf(fmaxf(x, -10.f), 10.f);
  float e = __expf(2.f * xc);
  return (e - 1.f) / (e + 1.f);
}

// ---------------- runtime dtype detection ---------------------------------
__global__ void detect_dtype(const unsigned int* __restrict__ words,
                             int* __restrict__ is_bf16) {
  const int lane = threadIdx.x;
  int cnt = 0;
  for (int i = 0; i < 64; i++) {
    const unsigned int w = words[lane + i * 64];
    const int e = (w >> 7) & 0xFF;
    cnt += (e >= 100 && e <= 135) ? 1 : 0;
  }
  for (int off = 32; off > 0; off >>= 1) cnt += __shfl_down(cnt, off);
  if (lane == 0) *is_bf16 = (cnt >= 2048) ? 1 : 0;
}

// ---------------- batched input normalization -> canonical bf16 -----------
struct ConvDesc { const void* src; bf16* dst; int n; };
struct ConvPack { ConvDesc d[15]; };

__global__ __launch_bounds__(256) void convert_all(ConvPack p,
                                                   const int* __restrict__ flag,
                                                   float* __restrict__ h0a,
                                                   float* __restrict__ h0b) {
  const int ti = blockIdx.y;
  const ConvDesc d = p.d[ti];
  const int bf = *flag;
  const long stride = (long)gridDim.x * 256 * 8;
  for (long base = ((long)blockIdx.x * 256 + threadIdx.x) * 8; base < d.n;
       base += stride) {
    if (base + 8 <= d.n) {
      float f[8];
      if (bf) {
        const uint4 v = *(const uint4*)((const char*)d.src + base * 2);
        *(uint4*)((char*)d.dst + base * 2) = v;
        if (ti == 0 && h0a) {
          const bf16* bv = (const bf16*)&v;
#pragma unroll
          for (int e = 0; e < 8; e++) f[e] = (float)bv[e];
        }
      } else {
        const float* s = (const float*)d.src + base;
        const float4 v0 = *(const float4*)s;
        const float4 v1 = *(const float4*)(s + 4);
        f[0] = v0.x; f[1] = v0.y; f[2] = v0.z; f[3] = v0.w;
        f[4] = v1.x; f[5] = v1.y; f[6] = v1.z; f[7] = v1.w;
        bf16 o[8];
#pragma unroll
        for (int e = 0; e < 8; e++) o[e] = (bf16)f[e];
        *(uint4*)((char*)d.dst + base * 2) = *(const uint4*)o;
      }
      if (ti == 0 && h0a) {
#pragma unroll
        for (int e = 0; e < 8; e++) { h0a[base + e] = f[e]; h0b[base + e] = f[e]; }
      }
    } else {
      for (long e = base; e < d.n; e++) {
        const float f = bf ? (float)((const bf16*)d.src)[e]
                           : ((const float*)d.src)[e];
        d.dst[e] = (bf16)f;
        if (ti == 0 && h0a) { h0a[e] = f; h0b[e] = f; }
      }
    }
  }
}

// ---------------- generic C = A[MxK] * B[NxK]^T (+bias, relu), bf16 out ----
template <bool RELU, bool GI_BIAS>
__global__ __launch_bounds__(256, 2) void gemm_bt(
    const bf16* __restrict__ A, const bf16* __restrict__ Bm,
    const bf16* __restrict__ bias1, const bf16* __restrict__ bias2,
    bf16* __restrict__ C, int K, int N)
{
  __shared__ __attribute__((aligned(16))) bf16 As[128 * 32];
  __shared__ __attribute__((aligned(16))) bf16 Bs[128 * 32];
  const int tid = threadIdx.x;
  const int wave = tid >> 6, lane = tid & 63;
  const int quad = lane >> 4, l16 = lane & 15;
  const int m0 = blockIdx.x * 128, n0 = blockIdx.y * 128;
  const int wm = (wave & 1) * 64, wn = (wave >> 1) * 64;
  f32x4 acc[4][4] = {};
  for (int k0 = 0; k0 < K; k0 += 32) {
#pragma unroll
    for (int rr = 0; rr < 2; rr++) {
      const int c = rr * 256 + tid;
      const int cg = (c & 3) ^ ((c >> 3) & 3);  // source swizzle
      gld_lds16(A + (size_t)(m0 + (c >> 2)) * K + (k0 + cg * 8),
                As + (size_t)(rr * 256 + wave * 64) * 8);
      gld_lds16(Bm + (size_t)(n0 + (c >> 2)) * K + (k0 + cg * 8),
                Bs + (size_t)(rr * 256 + wave * 64) * 8);
    }
    __syncthreads();
    bf16x8 af[4], bv[4];
#pragma unroll
    for (int t = 0; t < 4; t++) {
      const int ra = wm + t * 16 + l16;
      const int rb = wn + t * 16 + l16;
      af[t] = *(const bf16x8*)(As + (ra * 32 + (quad ^ ((ra >> 1) & 3)) * 8));
      bv[t] = *(const bf16x8*)(Bs + (rb * 32 + (quad ^ ((rb >> 1) & 3)) * 8));
    }
#pragma unroll
    for (int tm = 0; tm < 4; tm++)
#pragma unroll
      for (int tn = 0; tn < 4; tn++)
        acc[tm][tn] = __builtin_amdgcn_mfma_f32_16x16x32_bf16(af[tm], bv[tn], acc[tm][tn], 0, 0, 0);
    __syncthreads();
  }
#pragma unroll
  for (int tn = 0; tn < 4; tn++) {
    const int col = n0 + wn + tn * 16 + l16;
    float bias = (float)bias1[col];
    if (GI_BIAS) {
      if (col < 2 * H_DIM) bias += (float)bias2[col];  // fold bh into r,z gates only
    }
#pragma unroll
    for (int tm = 0; tm < 4; tm++) {
#pragma unroll
      for (int r = 0; r < 4; r++) {
        const int row = m0 + wm + tm * 16 + quad * 4 + r;
        float v = acc[tm][tn][r] + bias;
        if (RELU) v = fmaxf(v, 0.f);
        C[(size_t)row * N + col] = (bf16)v;
      }
    }
  }
}

// ---------------- fused GRU step ------------------------------------------
// Block: 64 batch rows x 64 hidden units, all 3 gate strips (packed N=192).
// 4 waves, each 16 rows x 192 cols -> acc[12] = 48 AGPR. After the K-loop
// the block's gi tile (64 rows x 3 gates x 64 j = 24 KB) is staged into LDS
// with 6 coalesced global_load_lds dwordx4 per thread (lane-linear chunks),
// replacing 48 scalar 2B global loads per thread in the epilogue.
struct GruArgs {
  const bf16* h_in16; const float* h_in32;
  bf16* h_out16; float* h_out32;
  const bf16* gi;    // [B][3H] bf16, bi(+bh for r,z) folded
  const bf16* wh;    // [3H][H]
  const bf16* bh;    // [3H] (need n-part)
  const bf16* fcw;   // [4][H]
  float* proj;       // [B][projT][4] fp32 accum
  int projT, t, relu;
};

__global__ __launch_bounds__(256, 4) void gru_step(GruArgs g1, GruArgs g2)
{
  const GruArgs G = (blockIdx.z == 0) ? g1 : g2;
  __shared__ __attribute__((aligned(16))) bf16 As[64 * 32];
  __shared__ __attribute__((aligned(16))) bf16 Bs[192 * 32];
  __shared__ __attribute__((aligned(16))) bf16 Gs[64 * 192];  // gi tile, 24 KB
  const int tid = threadIdx.x;
  const int wave = tid >> 6, lane = tid & 63;
  const int quad = lane >> 4, l16 = lane & 15;
  const int m0 = blockIdx.x * 64;
  const int j0 = blockIdx.y * 64;
  f32x4 acc[12] = {};
  for (int k0 = 0; k0 < H_DIM; k0 += 32) {
    {
      const int c = tid;                                 // 64 rows x 4 chunks
      const int cg = (c & 3) ^ ((c >> 3) & 3);
      gld_lds16(G.h_in16 + (size_t)(m0 + (c >> 2)) * H_DIM + (k0 + cg * 8),
                As + (size_t)(wave * 64) * 8);
    }
#pragma unroll
    for (int rr = 0; rr < 3; rr++) {
      const int c = rr * 256 + tid;
      const int p = c >> 2;                              // packed row 0..191
      const int cg = (c & 3) ^ ((c >> 3) & 3);
      const int grow = (p >> 6) * H_DIM + j0 + (p & 63); // gate*H + j
      gld_lds16(G.wh + (size_t)grow * H_DIM + (k0 + cg * 8),
                Bs + (size_t)(rr * 256 + wave * 64) * 8);
    }
    __syncthreads();
    const int ra = wave * 16 + l16;
    bf16x8 af = *(const bf16x8*)(As + (ra * 32 + (quad ^ ((ra >> 1) & 3)) * 8));
#pragma unroll
    for (int tn = 0; tn < 12; tn++) {
      const int rb = tn * 16 + l16;
      bf16x8 bv = *(const bf16x8*)(Bs + (rb * 32 + (quad ^ ((rb >> 1) & 3)) * 8));
      acc[tn] = __builtin_amdgcn_mfma_f32_16x16x32_bf16(af, bv, acc[tn], 0, 0, 0);
    }
    __syncthreads();
  }

  // ---- stage gi tile into LDS (lane-linear: chunk L = i*256+tid) ----
#pragma unroll
  for (int i = 0; i < 6; i++) {
    const int L = i * 256 + tid;        // chunk 0..1535; row = L/24, c = L%24
    const int row = L / 24, c = L % 24;
    gld_lds16(G.gi + (size_t)(m0 + row) * (3 * H_DIM) +
                  ((c >> 3) * H_DIM + j0 + (c & 7) * 8),
              Gs + (size_t)(i * 256 + wave * 64) * 8);
  }
  __syncthreads();

  // ---- epilogue: GRU cell + projection partials (gi from LDS) ----
  float pp[4][4];
#pragma unroll
  for (int r = 0; r < 4; r++)
#pragma unroll
    for (int i = 0; i < 4; i++) pp[r][i] = 0.f;

#pragma unroll
  for (int tj = 0; tj < 4; tj++) {
    const int jj = tj * 16 + l16;
    const int j = j0 + jj;
    const float bhn = (float)G.bh[2 * H_DIM + j];
    float fw[4];
#pragma unroll
    for (int i = 0; i < 4; i++) fw[i] = (float)G.fcw[i * H_DIM + j];
#pragma unroll
    for (int r = 0; r < 4; r++) {
      const int lrow = wave * 16 + quad * 4 + r;        // block-local row
      const int row = m0 + lrow;
      const float gr = (float)Gs[lrow * 192 + jj];
      const float gz = (float)Gs[lrow * 192 + 64 + jj];
      const float gn = (float)Gs[lrow * 192 + 128 + jj];
      const float hr = acc[tj][r];
      const float hz = acc[tj + 4][r];
      const float hn = acc[tj + 8][r];
      const float rg = sigm(gr + hr);
      const float zg = sigm(gz + hz);
      const float ng = tanh_fast(gn + rg * (hn + bhn));  // bh_n stays inside r*(...)
      const size_t hidx = (size_t)row * H_DIM + j;
      const float hold = G.h_in32 ? G.h_in32[hidx] : (float)G.h_in16[hidx];
      const float hnew = (1.f - zg) * ng + zg * hold;
      if (G.h_out32) G.h_out32[hidx] = hnew;
      G.h_out16[hidx] = (bf16)hnew;
      const float act = G.relu ? fmaxf(hnew, 0.f) : hnew;
#pragma unroll
      for (int i = 0; i < 4; i++) pp[r][i] += fw[i] * act;
    }
  }
#pragma unroll
  for (int r = 0; r < 4; r++)
#pragma unroll
    for (int i = 0; i < 4; i++) {
      float v = pp[r][i];
      v += __shfl_xor(v, 1);
      v += __shfl_xor(v, 2);
      v += __shfl_xor(v, 4);
      v += __shfl_xor(v, 8);
      if (l16 == 0) {
        const int row = m0 + wave * 16 + quad * 4 + r;
        atomicAdd(&G.proj[((size_t)row * G.projT + G.t) * 4 + i], v);
      }
    }
}

// ---------------- finalize: add fc biases, emit in detected dtype ---------
__global__ __launch_bounds__(256) void finalize(const float* __restrict__ p1,
                                                const float* __restrict__ p2,
                                                const bf16* __restrict__ fib,
                                                const bf16* __restrict__ fob,
                                                const int* __restrict__ flag,
                                                void* __restrict__ out, int n) {
  const int idx = blockIdx.x * 256 + threadIdx.x;
  if (idx >= n) return;
  const int R1 = B_DIM * T_PAST * 4;
  float v;
  if (idx < R1) {
    v = p1[idx] + (float)fib[idx & 3];
  } else {
    const int k = idx - R1;
    v = p2[k] + (float)fob[k & 3];
  }
  if (*flag) ((bf16*)out)[idx] = (bf16)v;
  else       ((float*)out)[idx] = v;
}

extern "C" void kernel_launch(void* const* d_in, const int* in_sizes, int n_in,
                              void* d_out, int out_size, void* d_ws, size_t ws_size,
                              hipStream_t stream)
{
  (void)n_in;
  char* w = (char*)d_ws;
  auto alloc = [&](size_t bytes) -> void* {
    void* p = (void*)w;
    w += (bytes + 255) & ~(size_t)255;
    return p;
  };
  int* flag = (int*)alloc(256);

  // canonical bf16 copies of the 15 tensor inputs
  bf16* canon[15];
  for (int i = 0; i < 15; i++) canon[i] = (bf16*)alloc((size_t)in_sizes[i] * 2);
  const bf16* ctx  = canon[0];
  const bf16* wc   = canon[1];
  const bf16* bc   = canon[2];
  const bf16* g1wi = canon[3];
  const bf16* g1wh = canon[4];
  const bf16* g1bi = canon[5];
  const bf16* g1bh = canon[6];
  const bf16* g2wi = canon[7];
  const bf16* g2wh = canon[8];
  const bf16* g2bi = canon[9];
  const bf16* g2bh = canon[10];
  const bf16* fiw  = canon[11];
  const bf16* fib  = canon[12];
  const bf16* fow  = canon[13];
  const bf16* fob  = canon[14];

  bf16* ec   = (bf16*)alloc((size_t)B_DIM * 512 * 2);
  bf16* gi1  = (bf16*)alloc((size_t)B_DIM * 3 * H_DIM * 2);
  bf16* gi2  = (bf16*)alloc((size_t)B_DIM * 3 * H_DIM * 2);
  bf16* h116[2] = {(bf16*)alloc((size_t)B_DIM * H_DIM * 2), (bf16*)alloc((size_t)B_DIM * H_DIM * 2)};
  bf16* h216[2] = {(bf16*)alloc((size_t)B_DIM * H_DIM * 2), (bf16*)alloc((size_t)B_DIM * H_DIM * 2)};
  float* proj1 = (float*)alloc((size_t)B_DIM * T_PAST * 4 * 4);
  float* proj2 = (float*)alloc((size_t)B_DIM * T_FUT * 4 * 4);
  float* h132[2] = {nullptr, nullptr};
  float* h232[2] = {nullptr, nullptr};
  const size_t used = (size_t)(w - (char*)d_ws);
  const size_t fp32_need = (size_t)4 * B_DIM * H_DIM * 4 + 4096;
  const bool fp32h = (ws_size > used) && ((ws_size - used) >= fp32_need);
  if (fp32h) {
    h132[0] = (float*)alloc((size_t)B_DIM * H_DIM * 4);
    h132[1] = (float*)alloc((size_t)B_DIM * H_DIM * 4);
    h232[0] = (float*)alloc((size_t)B_DIM * H_DIM * 4);
    h232[1] = (float*)alloc((size_t)B_DIM * H_DIM * 4);
  }

  // 1) detect input dtype (bf16 vs f32) from context values
  detect_dtype<<<1, 64, 0, stream>>>((const unsigned int*)d_in[0], flag);

  // 2) zero projection accumulators (ws is poisoned before every call)
  hipMemsetAsync(proj1, 0,
                 ((size_t)B_DIM * T_PAST * 4 + (size_t)B_DIM * T_FUT * 4) * 4, stream);

  // 3) normalize all inputs to canonical bf16 (+ fp32 master h from ctx)
  ConvPack cp;
  for (int i = 0; i < 15; i++) { cp.d[i].src = d_in[i]; cp.d[i].dst = canon[i]; cp.d[i].n = in_sizes[i]; }
  convert_all<<<dim3(4096, 15), 256, 0, stream>>>(cp, flag,
      fp32h ? h132[0] : nullptr, fp32h ? h232[0] : nullptr);

  // encoded_context = relu(ctx @ wc^T + bc)
  gemm_bt<true, false><<<dim3(64, 4), 256, 0, stream>>>(ctx, wc, bc, nullptr, ec, H_DIM, 512);
  // gi = ec @ wi^T + bi (+ bh for r,z gates)
  gemm_bt<false, true><<<dim3(64, 24), 256, 0, stream>>>(ec, g1wi, g1bi, g1bh, gi1, 512, 3 * H_DIM);
  gemm_bt<false, true><<<dim3(64, 24), 256, 0, stream>>>(ec, g2wi, g2bi, g2bh, gi2, 512, 3 * H_DIM);

  for (int t = 0; t < T_PAST; t++) {
    const int si = t & 1, so = (t + 1) & 1;
    GruArgs a1;
    a1.h_in16 = (t == 0) ? ctx : h116[si];
    a1.h_in32 = fp32h ? h132[si] : nullptr;
    a1.h_out16 = h116[so];
    a1.h_out32 = fp32h ? h132[so] : nullptr;
    a1.gi = gi1; a1.wh = g1wh; a1.bh = g1bh; a1.fcw = fiw;
    a1.proj = proj1; a1.projT = T_PAST; a1.t = t; a1.relu = 0;
    if (t < T_FUT) {
      GruArgs a2;
      a2.h_in16 = (t == 0) ? ctx : h216[si];
      a2.h_in32 = fp32h ? h232[si] : nullptr;
      a2.h_out16 = h216[so];
      a2.h_out32 = fp32h ? h232[so] : nullptr;
      a2.gi = gi2; a2.wh = g2wh; a2.bh = g2bh; a2.fcw = fow;
      a2.proj = proj2; a2.projT = T_FUT; a2.t = t; a2.relu = 1;
      gru_step<<<dim3(128, 16, 2), 256, 0, stream>>>(a1, a2);
    } else {
      gru_step<<<dim3(128, 16, 1), 256, 0, stream>>>(a1, a1);
    }
  }

  finalize<<<dim3((out_size + 255) / 256), 256, 0, stream>>>(
      proj1, proj2, fib, fob, flag, d_out, out_size);
}